// Round 1
// baseline (2695.491 us; speedup 1.0000x reference)
//
#include <hip/hip_runtime.h>

// out = L @ features, L in COO (rows, cols, vals), features [N,64] f32.
// Baseline: 16 threads/edge, each handles a float4 chunk of the 64-float row.
// Gather coalesced (256B/edge); scatter via global_atomic_add_f32.

#define DFEAT 64

__global__ __launch_bounds__(256) void spmm_coo_atomic(
    const float* __restrict__ features,
    const int*   __restrict__ rows,
    const int*   __restrict__ cols,
    const float* __restrict__ vals,
    float*       __restrict__ out,
    int nnz)
{
    long long t = (long long)blockIdx.x * blockDim.x + threadIdx.x;
    long long e = t >> 4;               // edge index (16 threads per edge)
    if (e >= nnz) return;
    int c = ((int)t & 15) << 2;         // float offset within row: 0,4,...,60

    int   row = rows[e];
    int   col = cols[e];
    float v   = vals[e];

    const float4 f = *reinterpret_cast<const float4*>(
        features + (size_t)col * DFEAT + c);

    float* op = out + (size_t)row * DFEAT + c;
    atomicAdd(op + 0, v * f.x);
    atomicAdd(op + 1, v * f.y);
    atomicAdd(op + 2, v * f.z);
    atomicAdd(op + 3, v * f.w);
}

extern "C" void kernel_launch(void* const* d_in, const int* in_sizes, int n_in,
                              void* d_out, int out_size, void* d_ws, size_t ws_size,
                              hipStream_t stream) {
    const float* features = (const float*)d_in[0];
    const int*   rows     = (const int*)  d_in[1];
    const int*   cols     = (const int*)  d_in[2];
    const float* vals     = (const float*)d_in[3];
    float*       out      = (float*)      d_out;
    const int    nnz      = in_sizes[1];

    // Output is accumulated into — must zero every call (harness poisons once,
    // then replays without re-poisoning).
    hipMemsetAsync(d_out, 0, (size_t)out_size * sizeof(float), stream);

    const long long total_threads = (long long)nnz * 16;
    const int block = 256;
    const long long grid = (total_threads + block - 1) / block;
    spmm_coo_atomic<<<(unsigned)grid, block, 0, stream>>>(
        features, rows, cols, vals, out, nnz);
}

// Round 2
// 789.019 us; speedup vs baseline: 3.4163x; 3.4163x over previous
//
#include <hip/hip_runtime.h>

// out = L @ features, COO -> counting-sort edges by destination row -> per-row
// register accumulation with one coalesced store per row. No float atomics.
//
// ws layout: cnt[N] | cursor[N] | rowptr[N+1] | pad | edges[nnz] (int2: col, val-bits)

#define DFEAT 64
#define SCAN_BLOCK 1024

__global__ __launch_bounds__(256) void hist_kernel(
    const int* __restrict__ rows, int* __restrict__ cnt, int nnz)
{
    int e = blockIdx.x * blockDim.x + threadIdx.x;
    if (e < nnz) atomicAdd(&cnt[rows[e]], 1);
}

__global__ __launch_bounds__(SCAN_BLOCK) void scan_kernel(
    const int* __restrict__ cnt, int* __restrict__ rowptr,
    int* __restrict__ cursor, int n)
{
    __shared__ int part[SCAN_BLOCK];
    const int t = threadIdx.x;
    const int chunk = (n + SCAN_BLOCK - 1) / SCAN_BLOCK;
    const int beg = t * chunk;
    const int end = min(n, beg + chunk);

    int s = 0;
    for (int i = beg; i < end; ++i) s += cnt[i];
    part[t] = s;
    __syncthreads();

    // Hillis-Steele inclusive scan over the 1024 partials.
    for (int d = 1; d < SCAN_BLOCK; d <<= 1) {
        int v = (t >= d) ? part[t - d] : 0;
        __syncthreads();
        part[t] += v;
        __syncthreads();
    }

    int off = part[t] - s;  // exclusive prefix for this thread's chunk
    for (int i = beg; i < end; ++i) {
        int c = cnt[i];
        rowptr[i] = off;
        cursor[i] = off;
        off += c;
    }
    if (t == SCAN_BLOCK - 1) rowptr[n] = part[SCAN_BLOCK - 1];
}

__global__ __launch_bounds__(256) void scatter_kernel(
    const int* __restrict__ rows, const int* __restrict__ cols,
    const float* __restrict__ vals, int* __restrict__ cursor,
    int2* __restrict__ edges, int nnz)
{
    int e = blockIdx.x * blockDim.x + threadIdx.x;
    if (e < nnz) {
        int r = rows[e];
        int slot = atomicAdd(&cursor[r], 1);
        edges[slot] = make_int2(cols[e], __float_as_int(vals[e]));
    }
}

// One wave (64 lanes) per output row; lane = feature dim.
__global__ __launch_bounds__(256) void spmm_rows(
    const float* __restrict__ features, const int2* __restrict__ edges,
    const int* __restrict__ rowptr, float* __restrict__ out, int n)
{
    int wid  = (blockIdx.x * blockDim.x + threadIdx.x) >> 6;  // row
    int lane = threadIdx.x & 63;                              // feature dim
    if (wid >= n) return;

    const int beg = rowptr[wid];
    const int end = rowptr[wid + 1];

    float acc = 0.f;
    for (int base = beg; base < end; base += 64) {
        int m = end - base;
        if (m > 64) m = 64;
        int ecol = 0, eval = 0;
        if (base + lane < end) {
            int2 ed = edges[base + lane];   // cooperative coalesced edge load
            ecol = ed.x;
            eval = ed.y;
        }
        for (int j = 0; j < m; ++j) {
            int   c = __shfl(ecol, j);                      // broadcast edge j
            float v = __int_as_float(__shfl(eval, j));
            acc += v * features[(size_t)c * DFEAT + lane];  // coalesced 256B gather
        }
    }
    out[(size_t)wid * DFEAT + lane] = acc;  // single coalesced store per row
}

// ---- fallback (ws too small): round-1 atomic kernel ----
__global__ __launch_bounds__(256) void spmm_coo_atomic(
    const float* __restrict__ features, const int* __restrict__ rows,
    const int* __restrict__ cols, const float* __restrict__ vals,
    float* __restrict__ out, int nnz)
{
    long long t = (long long)blockIdx.x * blockDim.x + threadIdx.x;
    long long e = t >> 4;
    if (e >= nnz) return;
    int c = ((int)t & 15) << 2;
    int row = rows[e], col = cols[e];
    float v = vals[e];
    const float4 f = *reinterpret_cast<const float4*>(features + (size_t)col * DFEAT + c);
    float* op = out + (size_t)row * DFEAT + c;
    atomicAdd(op + 0, v * f.x);
    atomicAdd(op + 1, v * f.y);
    atomicAdd(op + 2, v * f.z);
    atomicAdd(op + 3, v * f.w);
}

extern "C" void kernel_launch(void* const* d_in, const int* in_sizes, int n_in,
                              void* d_out, int out_size, void* d_ws, size_t ws_size,
                              hipStream_t stream) {
    const float* features = (const float*)d_in[0];
    const int*   rows     = (const int*)  d_in[1];
    const int*   cols     = (const int*)  d_in[2];
    const float* vals     = (const float*)d_in[3];
    float*       out      = (float*)      d_out;
    const int    nnz      = in_sizes[1];
    const int    n_nodes  = in_sizes[0] / DFEAT;

    // ws layout
    char*  base       = (char*)d_ws;
    size_t off_cnt    = 0;
    size_t off_cursor = off_cnt    + (size_t)n_nodes * 4;
    size_t off_rowptr = off_cursor + (size_t)n_nodes * 4;
    size_t off_edges  = (off_rowptr + ((size_t)n_nodes + 1) * 4 + 7) & ~(size_t)7;
    size_t need       = off_edges + (size_t)nnz * 8;

    if (ws_size < need) {
        // fallback: direct atomic scatter-add
        hipMemsetAsync(d_out, 0, (size_t)out_size * sizeof(float), stream);
        const long long tt = (long long)nnz * 16;
        spmm_coo_atomic<<<(unsigned)((tt + 255) / 256), 256, 0, stream>>>(
            features, rows, cols, vals, out, nnz);
        return;
    }

    int*  cnt    = (int*) (base + off_cnt);
    int*  cursor = (int*) (base + off_cursor);
    int*  rowptr = (int*) (base + off_rowptr);
    int2* edges  = (int2*)(base + off_edges);

    hipMemsetAsync(cnt, 0, (size_t)n_nodes * 4, stream);

    const int eb = (nnz + 255) / 256;
    hist_kernel<<<eb, 256, 0, stream>>>(rows, cnt, nnz);
    scan_kernel<<<1, SCAN_BLOCK, 0, stream>>>(cnt, rowptr, cursor, n_nodes);
    scatter_kernel<<<eb, 256, 0, stream>>>(rows, cols, vals, cursor, edges, nnz);

    const long long total_threads = (long long)n_nodes * 64;
    spmm_rows<<<(unsigned)((total_threads + 255) / 256), 256, 0, stream>>>(
        features, edges, rowptr, out, n_nodes);
}